// Round 12
// baseline (43793.399 us; speedup 1.0000x reference)
//
#include <hip/hip_runtime.h>

#define T_STEPS 2048
#define S_IN    512
#define H_DIM   2048
#define O_DIM   512
#define G4      (4 * H_DIM)   // 8192 gate rows per layer
#define ROW_U4  (H_DIM / 8)   // 256 uint4 per 2048-wide int16 row

// ---------------------------------------------------------------------------
// Per-matrix absmax reduction (atomicMax on positive-float bit pattern)
// ---------------------------------------------------------------------------
__global__ __launch_bounds__(256) void absmax_k(
    const float4* __restrict__ in, unsigned* __restrict__ out_bits, int n4)
{
    int i = blockIdx.x * 256 + threadIdx.x;
    const int stride = gridDim.x * 256;
    float m = 0.f;
    for (; i < n4; i += stride) {
        float4 v = in[i];
        m = fmaxf(m, fmaxf(fmaxf(fabsf(v.x), fabsf(v.y)),
                           fmaxf(fabsf(v.z), fabsf(v.w))));
    }
    #pragma unroll
    for (int off = 32; off > 0; off >>= 1) m = fmaxf(m, __shfl_xor(m, off, 64));
    __shared__ float red[4];
    const int lane = threadIdx.x & 63, w = threadIdx.x >> 6;
    if (lane == 0) red[w] = m;
    __syncthreads();
    if (threadIdx.x == 0) {
        m = fmaxf(fmaxf(red[0], red[1]), fmaxf(red[2], red[3]));
        atomicMax(out_bits, __float_as_uint(m));   // positive floats order as uints
    }
}

// ---------------------------------------------------------------------------
// fp32 -> int16 symmetric quantization: q = round(w * 32767 / smax)
// ---------------------------------------------------------------------------
__global__ __launch_bounds__(256) void quant_i16(
    const float4* __restrict__ in, short4* __restrict__ outp,
    const unsigned* __restrict__ scale_bits, int n4)
{
    const float smax = __uint_as_float(*scale_bits);
    const float invq = (smax > 0.f) ? (32767.0f / smax) : 0.f;
    int i = blockIdx.x * 256 + threadIdx.x;
    const int stride = gridDim.x * 256;
    for (; i < n4; i += stride) {
        float4 v = in[i];
        short4 o;
        o.x = (short)__float2int_rn(v.x * invq);
        o.y = (short)__float2int_rn(v.y * invq);
        o.z = (short)__float2int_rn(v.z * invq);
        o.w = (short)__float2int_rn(v.w * invq);
        outp[i] = o;
    }
}

// ---------------------------------------------------------------------------
// Generic tiled fp32 GEMM:  C[M][N] = A[M][K] * B[N][K]^T + bias0[n] (+bias1[n])
// M,N multiples of 64; K multiple of 32. 256 threads, 4x4 per thread.
// ---------------------------------------------------------------------------
#define BM 64
#define BN 64
#define BK 32

__global__ __launch_bounds__(256) void gemm_nt_bias(
    const float* __restrict__ A, const float* __restrict__ B,
    const float* __restrict__ bias0, const float* __restrict__ bias1,
    float* __restrict__ C, int M, int N, int K)
{
    __shared__ float As[BK][BM + 4];
    __shared__ float Bs[BK][BN + 4];
    const int tid = threadIdx.x;
    const int bn  = blockIdx.x * BN;
    const int bm  = blockIdx.y * BM;
    const int tr  = tid >> 4;
    const int tc  = tid & 15;

    float acc[4][4] = {};

    for (int k0 = 0; k0 < K; k0 += BK) {
        #pragma unroll
        for (int p = 0; p < 2; ++p) {
            int f   = tid + p * 256;
            int row = f >> 3;
            int c4  = (f & 7) << 2;
            float4 av = *(const float4*)(A + (size_t)(bm + row) * K + k0 + c4);
            float4 bv = *(const float4*)(B + (size_t)(bn + row) * K + k0 + c4);
            As[c4 + 0][row] = av.x; As[c4 + 1][row] = av.y;
            As[c4 + 2][row] = av.z; As[c4 + 3][row] = av.w;
            Bs[c4 + 0][row] = bv.x; Bs[c4 + 1][row] = bv.y;
            Bs[c4 + 2][row] = bv.z; Bs[c4 + 3][row] = bv.w;
        }
        __syncthreads();
        #pragma unroll
        for (int kk = 0; kk < BK; ++kk) {
            float4 a4 = *(const float4*)&As[kk][tr << 2];
            float4 b4 = *(const float4*)&Bs[kk][tc << 2];
            float a[4] = {a4.x, a4.y, a4.z, a4.w};
            float b[4] = {b4.x, b4.y, b4.z, b4.w};
            #pragma unroll
            for (int i = 0; i < 4; ++i)
                #pragma unroll
                for (int j = 0; j < 4; ++j)
                    acc[i][j] = fmaf(a[i], b[j], acc[i][j]);
        }
        __syncthreads();
    }

    const int col = bn + (tc << 2);
    float4 bz = make_float4(0.f, 0.f, 0.f, 0.f);
    if (bias0) { bz.x += bias0[col]; bz.y += bias0[col+1]; bz.z += bias0[col+2]; bz.w += bias0[col+3]; }
    if (bias1) { bz.x += bias1[col]; bz.y += bias1[col+1]; bz.z += bias1[col+2]; bz.w += bias1[col+3]; }
    #pragma unroll
    for (int i = 0; i < 4; ++i) {
        int row = bm + (tr << 2) + i;
        float4 o = make_float4(acc[i][0] + bz.x, acc[i][1] + bz.y,
                               acc[i][2] + bz.z, acc[i][3] + bz.w);
        *(float4*)(C + (size_t)row * N + col) = o;
    }
}

// ---------------------------------------------------------------------------
// One LSTM timestep, BOTH layers, lag-pipelined:
//   launch i: L0 computes h0[i]   (needs h0[i-1])          [if i < T]
//             L1 computes h1[i-1] (needs h0[i-1], h1[i-2]) [if i >= 1]
// All cross-step dependencies are satisfied by launch ordering on the stream
// (kernel boundaries = device-wide ordering + cache coherence). No cooperative
// launch, no grid barrier, no persistence -- maximally robust.
// Grid: 512 blocks x 256 threads; wave w of block b owns row jj = b*4+w for
// both layers (1 L0 row = 4 dots + 1 L1 row = 8 dots, each length 2048).
// ---------------------------------------------------------------------------
__device__ __forceinline__ float wave_allreduce(float v) {
    #pragma unroll
    for (int off = 32; off > 0; off >>= 1) v += __shfl_xor(v, off, 64);
    return v;
}
__device__ __forceinline__ float sigmoidf_(float x) { return 1.f / (1.f + expf(-x)); }
__device__ __forceinline__ float i16lo(unsigned v) { return (float)((int)(v << 16) >> 16); }
__device__ __forceinline__ float i16hi(unsigned v) { return (float)((int)v >> 16); }

// 8 int16 weights (one uint4) FMA'd against 8 fp32 h values (two float4s)
#define QFMA8(acc, wv, ha, hb)                        \
    acc = fmaf(i16lo((wv).x), (ha).x, acc);           \
    acc = fmaf(i16hi((wv).x), (ha).y, acc);           \
    acc = fmaf(i16lo((wv).y), (ha).z, acc);           \
    acc = fmaf(i16hi((wv).y), (ha).w, acc);           \
    acc = fmaf(i16lo((wv).z), (hb).x, acc);           \
    acc = fmaf(i16hi((wv).z), (hb).y, acc);           \
    acc = fmaf(i16lo((wv).w), (hb).z, acc);           \
    acc = fmaf(i16hi((wv).w), (hb).w, acc);

__global__ __launch_bounds__(256) void lstm_step(
    const float* __restrict__ Xp,      // [T][8192] = x@Wih0^T + b_ih0 + b_hh0
    const uint4* __restrict__ Wq0,     // Whh0 int16 [8192][2048]
    const uint4* __restrict__ Wq1i,    // Wih1 int16 [8192][2048]
    const uint4* __restrict__ Wq1h,    // Whh1 int16 [8192][2048]
    const unsigned* __restrict__ scales,
    const float* __restrict__ bih1,
    const float* __restrict__ bhh1,
    const float* __restrict__ h0_prev, // h0[i-1] (zeros for i==0)
    float*       __restrict__ h0_cur,  // h0[i]
    const float* __restrict__ h1_prev, // h1[i-2] (zeros for i<=1)
    float*       __restrict__ h1_out,  // h1_all row i-1 (unused for i==0)
    float*       __restrict__ c0,      // [2048] layer-0 cell state
    float*       __restrict__ c1,      // [2048] layer-1 cell state
    int i)
{
    const int lane = threadIdx.x & 63;
    const int w    = threadIdx.x >> 6;
    const int jj   = blockIdx.x * 4 + w;   // 0..2047

    // ---- Layer 0: h0[i] = cell(h0[i-1]; Whh0) + Xp[i] ----
    if (i < T_STEPS) {
        const float dq0 = __uint_as_float(scales[0]) * (1.0f / 32767.0f);
        const float4* h4 = (const float4*)h0_prev;
        const uint4* wp[4];
        #pragma unroll
        for (int g = 0; g < 4; ++g)
            wp[g] = Wq0 + (size_t)(g * H_DIM + jj) * ROW_U4;
        float a[4] = {0.f, 0.f, 0.f, 0.f};
        #pragma unroll
        for (int it = 0; it < 4; ++it) {
            const int idx = it * 64 + lane;
            float4 ha = h4[2 * idx], hb = h4[2 * idx + 1];
            #pragma unroll
            for (int g = 0; g < 4; ++g) {
                uint4 u = wp[g][idx];
                QFMA8(a[g], u, ha, hb);
            }
        }
        #pragma unroll
        for (int g = 0; g < 4; ++g) a[g] = wave_allreduce(a[g]);
        if (lane == 0) {
            const size_t xb = (size_t)i * G4;
            float gi = fmaf(a[0], dq0, Xp[xb + 0 * H_DIM + jj]);
            float gf = fmaf(a[1], dq0, Xp[xb + 1 * H_DIM + jj]);
            float gg = fmaf(a[2], dq0, Xp[xb + 2 * H_DIM + jj]);
            float go = fmaf(a[3], dq0, Xp[xb + 3 * H_DIM + jj]);
            float ii = sigmoidf_(gi), ff = sigmoidf_(gf);
            float g_ = tanhf(gg),     oo = sigmoidf_(go);
            float cn = ff * c0[jj] + ii * g_;
            c0[jj] = cn;
            h0_cur[jj] = oo * tanhf(cn);
        }
    }

    // ---- Layer 1: h1[i-1] = cell(h0[i-1], h1[i-2]; Wih1, Whh1) ----
    if (i >= 1) {
        const float dq1i = __uint_as_float(scales[1]) * (1.0f / 32767.0f);
        const float dq1h = __uint_as_float(scales[2]) * (1.0f / 32767.0f);
        const float4* x4 = (const float4*)h0_prev;
        const float4* y4 = (const float4*)h1_prev;
        const uint4 *wi[4], *wh[4];
        #pragma unroll
        for (int g = 0; g < 4; ++g) {
            wi[g] = Wq1i + (size_t)(g * H_DIM + jj) * ROW_U4;
            wh[g] = Wq1h + (size_t)(g * H_DIM + jj) * ROW_U4;
        }
        float ai[4] = {0.f, 0.f, 0.f, 0.f};
        float ah[4] = {0.f, 0.f, 0.f, 0.f};
        #pragma unroll
        for (int it = 0; it < 4; ++it) {
            const int idx = it * 64 + lane;
            float4 xa = x4[2 * idx], xb2 = x4[2 * idx + 1];
            float4 ya = y4[2 * idx], yb  = y4[2 * idx + 1];
            #pragma unroll
            for (int g = 0; g < 4; ++g) {
                uint4 u = wi[g][idx];
                QFMA8(ai[g], u, xa, xb2);
                uint4 v = wh[g][idx];
                QFMA8(ah[g], v, ya, yb);
            }
        }
        float s[4];
        #pragma unroll
        for (int g = 0; g < 4; ++g)
            s[g] = wave_allreduce(fmaf(ai[g], dq1i, ah[g] * dq1h));
        if (lane == 0) {
            float g0 = s[0] + bih1[0 * H_DIM + jj] + bhh1[0 * H_DIM + jj];
            float g1 = s[1] + bih1[1 * H_DIM + jj] + bhh1[1 * H_DIM + jj];
            float g2 = s[2] + bih1[2 * H_DIM + jj] + bhh1[2 * H_DIM + jj];
            float g3 = s[3] + bih1[3 * H_DIM + jj] + bhh1[3 * H_DIM + jj];
            float ii = sigmoidf_(g0), ff = sigmoidf_(g1);
            float g_ = tanhf(g2),     oo = sigmoidf_(g3);
            float cn = ff * c1[jj] + ii * g_;
            c1[jj] = cn;
            h1_out[jj] = oo * tanhf(cn);
        }
    }
}

// ---------------------------------------------------------------------------
// Row softmax over O_DIM=512, one block per row.
// ---------------------------------------------------------------------------
__global__ __launch_bounds__(256) void softmax_rows(
    const float* __restrict__ logits, float* __restrict__ out)
{
    const int t   = blockIdx.x;
    const int tid = threadIdx.x;
    const int w   = tid >> 6, lane = tid & 63;
    const float* row = logits + (size_t)t * O_DIM;
    float v0 = row[tid], v1 = row[tid + 256];

    __shared__ float red[4];
    float m = fmaxf(v0, v1);
    #pragma unroll
    for (int off = 32; off > 0; off >>= 1) m = fmaxf(m, __shfl_xor(m, off, 64));
    if (lane == 0) red[w] = m;
    __syncthreads();
    m = fmaxf(fmaxf(red[0], red[1]), fmaxf(red[2], red[3]));
    __syncthreads();

    float e0 = expf(v0 - m), e1 = expf(v1 - m);
    float s = e0 + e1;
    #pragma unroll
    for (int off = 32; off > 0; off >>= 1) s += __shfl_xor(s, off, 64);
    if (lane == 0) red[w] = s;
    __syncthreads();
    s = red[0] + red[1] + red[2] + red[3];
    float inv = 1.f / s;
    out[(size_t)t * O_DIM + tid]       = e0 * inv;
    out[(size_t)t * O_DIM + tid + 256] = e1 * inv;
}

// ---------------------------------------------------------------------------
extern "C" void kernel_launch(void* const* d_in, const int* in_sizes, int n_in,
                              void* d_out, int out_size, void* d_ws, size_t ws_size,
                              hipStream_t stream)
{
    const float* x     = (const float*)d_in[0];
    const float* W_ih0 = (const float*)d_in[1];
    const float* W_hh0 = (const float*)d_in[2];
    const float* b_ih0 = (const float*)d_in[3];
    const float* b_hh0 = (const float*)d_in[4];
    const float* W_ih1 = (const float*)d_in[5];
    const float* W_hh1 = (const float*)d_in[6];
    const float* b_ih1 = (const float*)d_in[7];
    const float* b_hh1 = (const float*)d_in[8];
    const float* W_out = (const float*)d_in[9];
    const float* b_out = (const float*)d_in[10];
    float* out = (float*)d_out;

    // ws layout (fp32 elems unless noted), total ~188.9 MB:
    //   Xp[T*G4] | h1_all[T*H] | logits[T*O] | h0buf[2*H] | zvec[H] | c0[H] |
    //   c1[H] | scales[4 u32] | Wq0,Wq1i,Wq1h (int16, 3*16M)
    float* ws      = (float*)d_ws;
    float* Xp      = ws;
    float* h1_all  = Xp     + (size_t)T_STEPS * G4;
    float* logits  = h1_all + (size_t)T_STEPS * H_DIM;
    float* h0buf   = logits + (size_t)T_STEPS * O_DIM;
    float* zvec    = h0buf + 2 * H_DIM;
    float* c0      = zvec  + H_DIM;
    float* c1      = c0    + H_DIM;
    unsigned* scales = (unsigned*)(c1 + H_DIM);
    short* Wq0  = (short*)(scales + 4);
    short* Wq1i = Wq0  + (size_t)G4 * H_DIM;
    short* Wq1h = Wq1i + (size_t)G4 * H_DIM;

    // zero zvec, c0, c1, scales (contiguous block)
    hipMemsetAsync(zvec, 0, (size_t)3 * H_DIM * sizeof(float) + 4 * sizeof(unsigned), stream);

    const int n4 = (G4 * H_DIM) / 4;   // float4s per matrix

    // Phase 0: device-side absmax + int16 quantize of recurrent matrices
    absmax_k<<<1024, 256, 0, stream>>>((const float4*)W_hh0, scales + 0, n4);
    absmax_k<<<1024, 256, 0, stream>>>((const float4*)W_ih1, scales + 1, n4);
    absmax_k<<<1024, 256, 0, stream>>>((const float4*)W_hh1, scales + 2, n4);
    quant_i16<<<2048, 256, 0, stream>>>((const float4*)W_hh0, (short4*)Wq0,  scales + 0, n4);
    quant_i16<<<2048, 256, 0, stream>>>((const float4*)W_ih1, (short4*)Wq1i, scales + 1, n4);
    quant_i16<<<2048, 256, 0, stream>>>((const float4*)W_hh1, (short4*)Wq1h, scales + 2, n4);

    // Phase A: Xp = x @ W_ih0^T + b_ih0 + b_hh0
    gemm_nt_bias<<<dim3(G4 / BN, T_STEPS / BM), 256, 0, stream>>>(
        x, W_ih0, b_ih0, b_hh0, Xp, T_STEPS, G4, S_IN);

    // Phase B: 2049 sequential step launches (lag-pipelined dual layer)
    for (int i = 0; i <= T_STEPS; ++i) {
        const float* h0p = (i == 0) ? zvec : h0buf + ((size_t)((i - 1) & 1)) * H_DIM;
        float*       h0c = h0buf + ((size_t)(i & 1)) * H_DIM;
        const float* h1p = (i <= 1) ? zvec : h1_all + (size_t)(i - 2) * H_DIM;
        float*       h1o = (i >= 1) ? h1_all + (size_t)(i - 1) * H_DIM : h0buf; // unused at i==0
        lstm_step<<<dim3(512), 256, 0, stream>>>(
            Xp, (const uint4*)Wq0, (const uint4*)Wq1i, (const uint4*)Wq1h,
            scales, b_ih1, b_hh1, h0p, h0c, h1p, h1o, c0, c1, i);
    }

    // Phase C: logits = h1_all @ W_out^T + b_out
    gemm_nt_bias<<<dim3(O_DIM / BN, T_STEPS / BM), 256, 0, stream>>>(
        h1_all, W_out, b_out, nullptr, logits, T_STEPS, O_DIM, H_DIM);

    // Phase D: row softmax -> d_out  [T,1,O]
    softmax_rows<<<dim3(T_STEPS), 256, 0, stream>>>(logits, out);
}